// Round 3
// baseline (547.581 us; speedup 1.0000x reference)
//
#include <hip/hip_runtime.h>
#include <hip/hip_bf16.h>
#include <stdint.h>

typedef __attribute__((ext_vector_type(8))) short short8;
typedef __attribute__((ext_vector_type(4))) float floatx4;

#define MODE_PROJ_T 0  // bf16 out, +bias, transposed per-batch store
#define MODE_PROJ_N 1  // bf16 out, +bias, normal store
#define MODE_SCORES 2  // f32 out, *alpha, no bias, batched
#define MODE_ATT    3  // bf16 out, no bias, batched
#define MODE_OUT    4  // f32 out, +bias, normal

__device__ __forceinline__ unsigned short f2bf(float f) {
    union { float f; unsigned int u; } x; x.f = f;
    unsigned int u = x.u + 0x7FFFu + ((x.u >> 16) & 1u);  // RNE
    return (unsigned short)(u >> 16);
}

__device__ __forceinline__ void gload_lds16(const void* g, void* lds) {
    __builtin_amdgcn_global_load_lds(
        (const __attribute__((address_space(1))) unsigned int*)g,
        (__attribute__((address_space(3))) unsigned int*)lds,
        16, 0, 0);
}

// ---- 256x256-tile 8-phase GEMM (T2+T3+T4+T5 template, m248-faithful) ----
// NT GEMM: C[m,n] = alpha * sum_k A[m,k]*B[n,k] (+ bias[n]), lda=ldb=1024.
// 512 threads = 8 waves (2M x 4N); per-wave C = 128x64; BK=64; LDS 128KiB dbuf.
// LDS swizzle: slot s of row r holds k-block (s ^ (r&7)) — conflict-free for
// 8-lane b128 service groups (XOR bijects l7 onto 8 distinct 16B bank groups).
// Phase schedule per tile t (stage issued FIRST per phase, T14 issue-early):
//   p0: stage(t+1,B-H0)->nxt | read A(m0-3),B(n0-1) | MFMA Q(m0-3,n0-1)
//   p1: stage(t+2,A-H0)->cur | read B(n2-3)         | MFMA Q(m0-3,n2-3)
//   p2: stage(t+2,B-H1)->cur | read A(m4-7)         | MFMA Q(m4-7,n2-3)
//   p3: stage(t+2,A-H1)->cur |                      | MFMA Q(m4-7,n0-1) | vmcnt(6)
// Safety: each staged region's readers complete before the preceding
// post-MFMA barrier (explicit lgkmcnt(0) before each MFMA cluster).

#define SCHED_PIN() __builtin_amdgcn_sched_barrier(0)

__device__ __forceinline__ void stage_half_A(
    const __hip_bfloat16* __restrict__ Ab, short* lds,
    int row0, int k0, int h, int wid, int lane)
{
    const int rl = lane >> 3, sl = lane & 7;
    const int gcol = k0 + ((sl ^ rl) << 3);
#pragma unroll
    for (int j = 0; j < 2; j++) {
        const int c = wid * 2 + j;                                 // 0..15
        const int lrow = ((c >> 3) << 7) + h * 64 + ((c & 7) << 3);
        gload_lds16(Ab + (size_t)(row0 + lrow + rl) * 1024 + gcol, lds + lrow * 64);
    }
}

__device__ __forceinline__ void stage_half_B(
    const __hip_bfloat16* __restrict__ Bb, short* lds,
    int col0, int k0, int h, int wid, int lane)
{
    const int rl = lane >> 3, sl = lane & 7;
    const int gcol = k0 + ((sl ^ rl) << 3);
#pragma unroll
    for (int j = 0; j < 2; j++) {
        const int c = wid * 2 + j;                                 // 0..15
        const int lrow = ((c >> 2) << 6) + h * 32 + ((c & 3) << 3);
        gload_lds16(Bb + (size_t)(col0 + lrow + rl) * 1024 + gcol, lds + lrow * 64);
    }
}

template<int MODE>
__device__ __forceinline__ void gemm_body8(
    const __hip_bfloat16* __restrict__ A,
    const __hip_bfloat16* __restrict__ Bm,
    const float* __restrict__ bias,
    void* __restrict__ Cout,
    int K, long sA, long sB, long sC, float alpha,
    int row0, int col0, int bz, short* As0, short* Bs0)
{
    const int tid  = threadIdx.x;
    const int wid  = tid >> 6;
    const int lane = tid & 63;
    const int wm = wid >> 2, wn = wid & 3;
    const int l15 = lane & 15, quad = lane >> 4, l7 = lane & 7;

    const __hip_bfloat16* Ab = A  + (size_t)bz * sA;
    const __hip_bfloat16* Bb = Bm + (size_t)bz * sB;
    const int NT = K >> 6;

    floatx4 acc[8][4];
#pragma unroll
    for (int i = 0; i < 8; i++)
#pragma unroll
        for (int j = 0; j < 4; j++) acc[i][j] = (floatx4){0.f, 0.f, 0.f, 0.f};

    // ---- prologue: tile0 fully + tile1 (3 of 4 halves) ----
    stage_half_B(Bb, Bs0, col0, 0, 0, wid, lane);
    stage_half_A(Ab, As0, row0, 0, 0, wid, lane);
    stage_half_B(Bb, Bs0, col0, 0, 1, wid, lane);
    stage_half_A(Ab, As0, row0, 0, 1, wid, lane);
    asm volatile("s_waitcnt vmcnt(4)" ::: "memory");
    stage_half_A(Ab, As0 + 16384, row0, 64, 0, wid, lane);
    stage_half_B(Bb, Bs0 + 16384, col0, 64, 1, wid, lane);
    stage_half_A(Ab, As0 + 16384, row0, 64, 1, wid, lane);
    asm volatile("s_waitcnt vmcnt(6)" ::: "memory");
    __builtin_amdgcn_s_barrier();

    for (int t = 0; t < NT; ++t) {
        const int d = t & 1;
        short* Asd = As0 + d * 16384;
        short* Bsd = Bs0 + d * 16384;
        short* Bsn = Bs0 + (d ^ 1) * 16384;
        const int k1 = (t + 1) << 6, k2 = (t + 2) << 6;
        short8 af[4][2], bfr[4][2];

        // ================= phase 0 =================
        if (t + 1 < NT) stage_half_B(Bb, Bsn, col0, k1, 0, wid, lane);
#pragma unroll
        for (int mt = 0; mt < 4; mt++)
#pragma unroll
            for (int ks = 0; ks < 2; ks++)
                af[mt][ks] = *(const short8*)&Asd[(wm * 128 + mt * 16 + l15) * 64 +
                                                  ((((ks << 2) + quad) ^ l7) << 3)];
#pragma unroll
        for (int nt = 0; nt < 2; nt++)
#pragma unroll
            for (int ks = 0; ks < 2; ks++)
                bfr[nt][ks] = *(const short8*)&Bsd[(wn * 64 + nt * 16 + l15) * 64 +
                                                   ((((ks << 2) + quad) ^ l7) << 3)];
        asm volatile("s_waitcnt lgkmcnt(8)" ::: "memory");
        SCHED_PIN();
        __builtin_amdgcn_s_barrier();
        asm volatile("s_waitcnt lgkmcnt(0)" ::: "memory");
        SCHED_PIN();
        __builtin_amdgcn_s_setprio(1);
#pragma unroll
        for (int ks = 0; ks < 2; ks++)
#pragma unroll
            for (int mt = 0; mt < 4; mt++)
#pragma unroll
                for (int nt = 0; nt < 2; nt++)
                    acc[mt][nt] = __builtin_amdgcn_mfma_f32_16x16x32_bf16(
                        af[mt][ks], bfr[nt][ks], acc[mt][nt], 0, 0, 0);
        __builtin_amdgcn_s_setprio(0);
        SCHED_PIN();
        __builtin_amdgcn_s_barrier();

        // ================= phase 1 =================
        if (t + 2 < NT) stage_half_A(Ab, Asd, row0, k2, 0, wid, lane);
#pragma unroll
        for (int nt = 0; nt < 2; nt++)
#pragma unroll
            for (int ks = 0; ks < 2; ks++)
                bfr[2 + nt][ks] = *(const short8*)&Bsd[(wn * 64 + (2 + nt) * 16 + l15) * 64 +
                                                       ((((ks << 2) + quad) ^ l7) << 3)];
        SCHED_PIN();
        __builtin_amdgcn_s_barrier();
        asm volatile("s_waitcnt lgkmcnt(0)" ::: "memory");
        SCHED_PIN();
        __builtin_amdgcn_s_setprio(1);
#pragma unroll
        for (int ks = 0; ks < 2; ks++)
#pragma unroll
            for (int mt = 0; mt < 4; mt++)
#pragma unroll
                for (int nt = 0; nt < 2; nt++)
                    acc[mt][2 + nt] = __builtin_amdgcn_mfma_f32_16x16x32_bf16(
                        af[mt][ks], bfr[2 + nt][ks], acc[mt][2 + nt], 0, 0, 0);
        __builtin_amdgcn_s_setprio(0);
        SCHED_PIN();
        __builtin_amdgcn_s_barrier();

        // ================= phase 2 =================
        if (t + 2 < NT) stage_half_B(Bb, Bsd, col0, k2, 1, wid, lane);
#pragma unroll
        for (int mt = 0; mt < 4; mt++)
#pragma unroll
            for (int ks = 0; ks < 2; ks++)
                af[mt][ks] = *(const short8*)&Asd[(wm * 128 + (4 + mt) * 16 + l15) * 64 +
                                                  ((((ks << 2) + quad) ^ l7) << 3)];
        SCHED_PIN();
        __builtin_amdgcn_s_barrier();
        asm volatile("s_waitcnt lgkmcnt(0)" ::: "memory");
        SCHED_PIN();
        __builtin_amdgcn_s_setprio(1);
#pragma unroll
        for (int ks = 0; ks < 2; ks++)
#pragma unroll
            for (int mt = 0; mt < 4; mt++)
#pragma unroll
                for (int nt = 0; nt < 2; nt++)
                    acc[4 + mt][2 + nt] = __builtin_amdgcn_mfma_f32_16x16x32_bf16(
                        af[mt][ks], bfr[2 + nt][ks], acc[4 + mt][2 + nt], 0, 0, 0);
        __builtin_amdgcn_s_setprio(0);
        SCHED_PIN();
        __builtin_amdgcn_s_barrier();

        // ================= phase 3 =================
        if (t + 2 < NT) stage_half_A(Ab, Asd, row0, k2, 1, wid, lane);
        SCHED_PIN();
        __builtin_amdgcn_s_barrier();
        __builtin_amdgcn_s_setprio(1);
#pragma unroll
        for (int ks = 0; ks < 2; ks++)
#pragma unroll
            for (int mt = 0; mt < 4; mt++)
#pragma unroll
                for (int nt = 0; nt < 2; nt++)
                    acc[4 + mt][nt] = __builtin_amdgcn_mfma_f32_16x16x32_bf16(
                        af[mt][ks], bfr[nt][ks], acc[4 + mt][nt], 0, 0, 0);
        __builtin_amdgcn_s_setprio(0);
        SCHED_PIN();
        if (t + 2 < NT) asm volatile("s_waitcnt vmcnt(6)" ::: "memory");
        else            asm volatile("s_waitcnt vmcnt(0)" ::: "memory");
        __builtin_amdgcn_s_barrier();
    }

    // ---- epilogue: C/D layout col=lane&15, row=quad*4+reg [m89/m91-verified] ----
#pragma unroll
    for (int nt = 0; nt < 4; nt++) {
        const int col = col0 + wn * 64 + nt * 16 + l15;
        float bv = 0.f;
        if (MODE == MODE_PROJ_T || MODE == MODE_PROJ_N || MODE == MODE_OUT) bv = bias[col];
#pragma unroll
        for (int mt = 0; mt < 8; mt++) {
            const int rbase = row0 + wm * 128 + mt * 16 + quad * 4;
            if (MODE == MODE_PROJ_T) {
                // 4 consecutive rows per lane are contiguous ushorts: one 8B store
                ushort4 o;
                o.x = f2bf(acc[mt][nt][0] + bv); o.y = f2bf(acc[mt][nt][1] + bv);
                o.z = f2bf(acc[mt][nt][2] + bv); o.w = f2bf(acc[mt][nt][3] + bv);
                *(ushort4*)&((unsigned short*)Cout)[((size_t)(rbase >> 10) << 20) +
                                                    (size_t)col * 1024 + (rbase & 1023)] = o;
            } else {
#pragma unroll
                for (int r = 0; r < 4; r++) {
                    const int m = rbase + r;
                    float v = acc[mt][nt][r];
                    if (MODE == MODE_SCORES) v *= alpha;
                    v += bv;
                    if (MODE == MODE_SCORES) {
                        ((float*)Cout)[(size_t)bz * sC + (size_t)m * 1024 + col] = v;
                    } else if (MODE == MODE_OUT) {
                        ((float*)Cout)[(size_t)m * 1024 + col] = v;
                    } else { // MODE_PROJ_N || MODE_ATT
                        ((unsigned short*)Cout)[(size_t)bz * sC + (size_t)m * 1024 + col] = f2bf(v);
                    }
                }
            }
        }
    }
}

// batched / single-matrix launches, XCD-aware decode (hw round-robins id%8)
template<int MODE>
__global__ __launch_bounds__(512, 2) void gemm8(
    const __hip_bfloat16* __restrict__ A,
    const __hip_bfloat16* __restrict__ Bm,
    const float* __restrict__ bias,
    void* __restrict__ Cout,
    int K, long sA, long sB, long sC, float alpha)
{
    __shared__ __align__(16) short As[2 * 256 * 64];
    __shared__ __align__(16) short Bs[2 * 256 * 64];
    const int id = blockIdx.x;
    const int xcd = id & 7;
    const int s   = id >> 3;
    int by, bx, bz;
    if (MODE == MODE_SCORES || MODE == MODE_ATT) {
        bz = xcd + ((s >> 4) << 3);        // batches {j, j+8} on XCD j
        by = (s & 15) >> 2;
        bx = s & 3;
    } else {                                // M=16384: 64 row-blocks x 4 col-blocks
        bz = 0;
        by = ((s >> 2) << 3) | xcd;        // y%8 == xcd
        bx = s & 3;
    }
    gemm_body8<MODE>(A, Bm, bias, Cout, K, sA, sB, sC, alpha,
                     by * 256, bx * 256, bz, As, Bs);
}

// all three input projections in ONE 768-block dispatch
__global__ __launch_bounds__(512, 2) void gemm8_proj3(
    const __hip_bfloat16* __restrict__ qb, const __hip_bfloat16* __restrict__ kb,
    const __hip_bfloat16* __restrict__ vb,
    const __hip_bfloat16* __restrict__ wq, const __hip_bfloat16* __restrict__ wk,
    const __hip_bfloat16* __restrict__ wv,
    const float* __restrict__ biq, const float* __restrict__ bik,
    const float* __restrict__ biv,
    unsigned short* __restrict__ qT, unsigned short* __restrict__ kp,
    unsigned short* __restrict__ vT)
{
    __shared__ __align__(16) short As[2 * 256 * 64];
    __shared__ __align__(16) short Bs[2 * 256 * 64];
    const int id  = blockIdx.x;
    const int xcd = id & 7;
    const int s   = id >> 3;           // 0..95
    const int g   = s >> 5;            // 0:q 1:k 2:v
    const int s2  = s & 31;
    const int by  = ((s2 >> 2) << 3) | xcd;
    const int bx  = s2 & 3;
    const __hip_bfloat16* A;  const __hip_bfloat16* B;  const float* bias;  void* C;
    if      (g == 0) { A = qb; B = wq; bias = biq; C = qT; }
    else if (g == 1) { A = kb; B = wk; bias = bik; C = kp; }
    else             { A = vb; B = wv; bias = biv; C = vT; }
    if (g == 1) gemm_body8<MODE_PROJ_N>(A, B, bias, C, 1024, 0, 0, 0, 1.f,
                                        by * 256, bx * 256, 0, As, Bs);
    else        gemm_body8<MODE_PROJ_T>(A, B, bias, C, 1024, 0, 0, 0, 1.f,
                                        by * 256, bx * 256, 0, As, Bs);
}

// one wave per 1024-float row; 4 rows per 256-thread block
__global__ __launch_bounds__(256) void softmax_rows(
    const float* __restrict__ S, unsigned short* __restrict__ A)
{
    const int row  = blockIdx.x * 4 + (threadIdx.x >> 6);
    const int lane = threadIdx.x & 63;
    const float4* p = (const float4*)(S + (size_t)row * 1024);
    float4 v[4];
    float mx = -3.0e38f;
#pragma unroll
    for (int i = 0; i < 4; i++) {
        v[i] = p[lane + i * 64];
        mx = fmaxf(mx, fmaxf(fmaxf(v[i].x, v[i].y), fmaxf(v[i].z, v[i].w)));
    }
#pragma unroll
    for (int off = 32; off >= 1; off >>= 1) mx = fmaxf(mx, __shfl_xor(mx, off, 64));
    float e[16], sum = 0.f;
#pragma unroll
    for (int i = 0; i < 4; i++) {
        e[i*4+0] = __expf(v[i].x - mx); e[i*4+1] = __expf(v[i].y - mx);
        e[i*4+2] = __expf(v[i].z - mx); e[i*4+3] = __expf(v[i].w - mx);
        sum += e[i*4+0] + e[i*4+1] + e[i*4+2] + e[i*4+3];
    }
#pragma unroll
    for (int off = 32; off >= 1; off >>= 1) sum += __shfl_xor(sum, off, 64);
    const float inv = 1.0f / sum;
    ushort4* out = (ushort4*)(A + (size_t)row * 1024);
#pragma unroll
    for (int i = 0; i < 4; i++) {
        ushort4 o;
        o.x = f2bf(e[i*4+0] * inv); o.y = f2bf(e[i*4+1] * inv);
        o.z = f2bf(e[i*4+2] * inv); o.w = f2bf(e[i*4+3] * inv);
        out[lane + i * 64] = o;
    }
}

// all 7 f32->bf16 conversions in ONE dispatch
__global__ __launch_bounds__(256) void cvt_all(
    const float* __restrict__ q, const float* __restrict__ k, const float* __restrict__ v,
    const float* __restrict__ wq, const float* __restrict__ wk,
    const float* __restrict__ wv, const float* __restrict__ wo,
    unsigned short* __restrict__ qb, unsigned short* __restrict__ kb, unsigned short* __restrict__ vb,
    unsigned short* __restrict__ wqb, unsigned short* __restrict__ wkb,
    unsigned short* __restrict__ wvb, unsigned short* __restrict__ wob)
{
    const int id = blockIdx.x;
    const float* src; unsigned short* dst; int base;
    if      (id < 16384) { src = q;  dst = qb;  base = 0; }
    else if (id < 32768) { src = k;  dst = kb;  base = 16384; }
    else if (id < 49152) { src = v;  dst = vb;  base = 32768; }
    else if (id < 50176) { src = wq; dst = wqb; base = 49152; }
    else if (id < 51200) { src = wk; dst = wkb; base = 50176; }
    else if (id < 52224) { src = wv; dst = wvb; base = 51200; }
    else                 { src = wo; dst = wob; base = 52224; }
    const int i = (id - base) * 256 + threadIdx.x;
    const float4 vv = ((const float4*)src)[i];
    ushort4 o; o.x = f2bf(vv.x); o.y = f2bf(vv.y); o.z = f2bf(vv.z); o.w = f2bf(vv.w);
    ((ushort4*)dst)[i] = o;
}

extern "C" void kernel_launch(void* const* d_in, const int* in_sizes, int n_in,
                              void* d_out, int out_size, void* d_ws, size_t ws_size,
                              hipStream_t stream) {
    const float* query = (const float*)d_in[0];
    const float* key   = (const float*)d_in[1];
    const float* value = (const float*)d_in[2];
    const float* Wq = (const float*)d_in[3];  const float* bq = (const float*)d_in[4];
    const float* Wk = (const float*)d_in[5];  const float* bk = (const float*)d_in[6];
    const float* Wv = (const float*)d_in[7];  const float* bv = (const float*)d_in[8];
    const float* Wo = (const float*)d_in[9];  const float* bo = (const float*)d_in[10];

    char* ws = (char*)d_ws;
    const size_t MB = 1ull << 20;
    unsigned short* qbf = (unsigned short*)(ws + 0   * MB);   // 32MB
    unsigned short* kbf = (unsigned short*)(ws + 32  * MB);   // 32MB
    unsigned short* vbf = (unsigned short*)(ws + 64  * MB);   // 32MB
    unsigned short* wqb = (unsigned short*)(ws + 96  * MB);   // 2MB
    unsigned short* wkb = (unsigned short*)(ws + 98  * MB);
    unsigned short* wvb = (unsigned short*)(ws + 100 * MB);
    unsigned short* wob = (unsigned short*)(ws + 102 * MB);
    unsigned short* qT  = (unsigned short*)(ws + 104 * MB);   // [B,E,T] 32MB
    unsigned short* kp  = (unsigned short*)(ws + 136 * MB);   // [B,S,E] 32MB
    unsigned short* vT  = (unsigned short*)(ws + 168 * MB);   // [B,E,S] 32MB
    float*          sc  = (float*)(ws + 0 * MB);              // overlay qbf+kbf, 64MB
    unsigned short* att = (unsigned short*)(ws + 64 * MB);    // overlay vbf, 32MB
    unsigned short* ob  = (unsigned short*)(ws + 104 * MB);   // overlay qT, 32MB

    const long S1M = 1 << 20;
    dim3 blk(256);
    dim3 blk5(512);

    cvt_all<<<53248, blk, 0, stream>>>(query, key, value, Wq, Wk, Wv, Wo,
                                       qbf, kbf, vbf, wqb, wkb, wvb, wob);

    // projections: M=16384, N=1024, K=1024 — one 768-block dispatch (256^2 tiles)
    gemm8_proj3<<<768, blk5, 0, stream>>>(
        (const __hip_bfloat16*)qbf, (const __hip_bfloat16*)kbf, (const __hip_bfloat16*)vbf,
        (const __hip_bfloat16*)wqb, (const __hip_bfloat16*)wkb, (const __hip_bfloat16*)wvb,
        bq, bk, bv, qT, kp, vT);

    // scores: per-batch 1024x1024, batch pinned to XCD
    gemm8<MODE_SCORES><<<256, blk5, 0, stream>>>(
        (const __hip_bfloat16*)qT, (const __hip_bfloat16*)kp, nullptr, sc, 1024,
        S1M, S1M, S1M, 0.03125f);

    softmax_rows<<<4096, blk, 0, stream>>>(sc, att);

    gemm8<MODE_ATT><<<256, blk5, 0, stream>>>(
        (const __hip_bfloat16*)att, (const __hip_bfloat16*)vT, nullptr, ob, 1024,
        S1M, S1M, S1M, 1.f);

    gemm8<MODE_OUT><<<256, blk5, 0, stream>>>(
        (const __hip_bfloat16*)ob, (const __hip_bfloat16*)wob, bo, d_out, 1024, 0, 0, 0, 1.f);
}

// Round 4
// 523.048 us; speedup vs baseline: 1.0469x; 1.0469x over previous
//
#include <hip/hip_runtime.h>
#include <hip/hip_bf16.h>
#include <stdint.h>

typedef __attribute__((ext_vector_type(8))) short short8;
typedef __attribute__((ext_vector_type(4))) float floatx4;

#define MODE_PROJ_T 0  // bf16 out, +bias, transposed per-batch store
#define MODE_PROJ_N 1  // bf16 out, +bias, normal store
#define MODE_SCORES 2  // f32 out, *alpha, no bias, batched
#define MODE_ATT    3  // bf16 out, no bias, batched
#define MODE_OUT    4  // f32 out, +bias, normal

__device__ __forceinline__ unsigned short f2bf(float f) {
    union { float f; unsigned int u; } x; x.f = f;
    unsigned int u = x.u + 0x7FFFu + ((x.u >> 16) & 1u);  // RNE
    return (unsigned short)(u >> 16);
}

__device__ __forceinline__ void gload_lds16(const void* g, void* lds) {
    __builtin_amdgcn_global_load_lds(
        (const __attribute__((address_space(1))) unsigned int*)g,
        (__attribute__((address_space(3))) unsigned int*)lds,
        16, 0, 0);
}

#define SCHED_PIN() __builtin_amdgcn_sched_barrier(0)
#define LGKM0() asm volatile("s_waitcnt lgkmcnt(0)" ::: "memory")

// ---- 256x256-tile 4-barrier pipelined GEMM ----
// NT GEMM: C[m,n] = alpha * sum_k A[m,k]*B[n,k] (+ bias[n]), lda=ldb=1024.
// 512 threads = 8 waves (2M x 4N); per-wave C = 128x64; BK=64; LDS 128KiB dbuf.
// LDS swizzle: slot s of row r holds k-block (s ^ (r&7)) — 0 conflicts (verified).
// Key idea vs r2/r3: ds_reads are issued in the window AFTER the MFMA cluster
// (or at the tile seam after vmcnt+barrier), and consumed a phase later —
// so the per-CU LDS pipe streams concurrently with the MFMA pipe instead of
// alternating in barrier-delimited bursts. One barrier per phase (4/tile).
// Cross-wave WAR safety: every staged region's readers finish at the
// lgkmcnt(0) of the phase BEFORE the stage's issue phase (barrier between);
// seam reads issue after all waves' vmcnt(6) (covers all 4 regions of t+1).

__device__ __forceinline__ void stage_half_A(
    const __hip_bfloat16* __restrict__ Ab, short* lds,
    int row0, int k0, int h, int wid, int lane)
{
    const int rl = lane >> 3, sl = lane & 7;
    const int gcol = k0 + ((sl ^ rl) << 3);
#pragma unroll
    for (int j = 0; j < 2; j++) {
        const int c = wid * 2 + j;                                 // 0..15
        const int lrow = ((c >> 3) << 7) + h * 64 + ((c & 7) << 3);
        gload_lds16(Ab + (size_t)(row0 + lrow + rl) * 1024 + gcol, lds + lrow * 64);
    }
}

__device__ __forceinline__ void stage_half_B(
    const __hip_bfloat16* __restrict__ Bb, short* lds,
    int col0, int k0, int h, int wid, int lane)
{
    const int rl = lane >> 3, sl = lane & 7;
    const int gcol = k0 + ((sl ^ rl) << 3);
#pragma unroll
    for (int j = 0; j < 2; j++) {
        const int c = wid * 2 + j;                                 // 0..15
        const int lrow = ((c >> 2) << 6) + h * 32 + ((c & 3) << 3);
        gload_lds16(Bb + (size_t)(col0 + lrow + rl) * 1024 + gcol, lds + lrow * 64);
    }
}

template<int MODE>
__device__ __forceinline__ void gemm_body8(
    const __hip_bfloat16* __restrict__ A,
    const __hip_bfloat16* __restrict__ Bm,
    const float* __restrict__ bias,
    void* __restrict__ Cout,
    int K, long sA, long sB, long sC, float alpha,
    int row0, int col0, int bz, short* As0, short* Bs0)
{
    const int tid  = threadIdx.x;
    const int wid  = tid >> 6;
    const int lane = tid & 63;
    const int wm = wid >> 2, wn = wid & 3;
    const int l15 = lane & 15, quad = lane >> 4, l7 = lane & 7;

    const __hip_bfloat16* Ab = A  + (size_t)bz * sA;
    const __hip_bfloat16* Bb = Bm + (size_t)bz * sB;
    const int NT = K >> 6;

    floatx4 acc[8][4];
#pragma unroll
    for (int i = 0; i < 8; i++)
#pragma unroll
        for (int j = 0; j < 4; j++) acc[i][j] = (floatx4){0.f, 0.f, 0.f, 0.f};

    short8 af[4][2], bfr[4][2];

    // fragment read sets (issue order is explicit at each call site)
    auto read_a03 = [&](const short* As_) {
#pragma unroll
        for (int mt = 0; mt < 4; mt++)
#pragma unroll
            for (int ks = 0; ks < 2; ks++)
                af[mt][ks] = *(const short8*)&As_[(wm * 128 + mt * 16 + l15) * 64 +
                                                  ((((ks << 2) + quad) ^ l7) << 3)];
    };
    auto read_a47 = [&](const short* As_) {
#pragma unroll
        for (int mt = 0; mt < 4; mt++)
#pragma unroll
            for (int ks = 0; ks < 2; ks++)
                af[mt][ks] = *(const short8*)&As_[(wm * 128 + (4 + mt) * 16 + l15) * 64 +
                                                  ((((ks << 2) + quad) ^ l7) << 3)];
    };
    auto read_b01 = [&](const short* Bs_) {
#pragma unroll
        for (int nt = 0; nt < 2; nt++)
#pragma unroll
            for (int ks = 0; ks < 2; ks++)
                bfr[nt][ks] = *(const short8*)&Bs_[(wn * 64 + nt * 16 + l15) * 64 +
                                                   ((((ks << 2) + quad) ^ l7) << 3)];
    };
    auto read_b23 = [&](const short* Bs_) {
#pragma unroll
        for (int nt = 0; nt < 2; nt++)
#pragma unroll
            for (int ks = 0; ks < 2; ks++)
                bfr[2 + nt][ks] = *(const short8*)&Bs_[(wn * 64 + (2 + nt) * 16 + l15) * 64 +
                                                       ((((ks << 2) + quad) ^ l7) << 3)];
    };

    // ---- prologue: tile0 fully + tile1 (3 of 4 halves) ----
    stage_half_B(Bb, Bs0, col0, 0, 0, wid, lane);
    stage_half_A(Ab, As0, row0, 0, 0, wid, lane);
    stage_half_B(Bb, Bs0, col0, 0, 1, wid, lane);
    stage_half_A(Ab, As0, row0, 0, 1, wid, lane);
    asm volatile("s_waitcnt vmcnt(4)" ::: "memory");
    stage_half_A(Ab, As0 + 16384, row0, 64, 0, wid, lane);
    stage_half_B(Bb, Bs0 + 16384, col0, 64, 1, wid, lane);
    stage_half_A(Ab, As0 + 16384, row0, 64, 1, wid, lane);
    asm volatile("s_waitcnt vmcnt(6)" ::: "memory");
    __builtin_amdgcn_s_barrier();
    // seam reads for tile 0 (all waves' vmcnt covered tile0 before the barrier)
    read_a03(As0); read_b01(Bs0);
    SCHED_PIN();

    for (int t = 0; t < NT; ++t) {
        const int d = t & 1;
        short* Asd = As0 + d * 16384;
        short* Bsd = Bs0 + d * 16384;
        short* Asn = As0 + (d ^ 1) * 16384;
        short* Bsn = Bs0 + (d ^ 1) * 16384;
        const int k1 = (t + 1) << 6, k2 = (t + 2) << 6;

        // ---- phase 0: wait A03/B01 -> Q1; then issue B23 reads ----
        if (t + 1 < NT) stage_half_B(Bb, Bsn, col0, k1, 0, wid, lane);
        LGKM0();
        SCHED_PIN();
        __builtin_amdgcn_s_setprio(1);
#pragma unroll
        for (int ks = 0; ks < 2; ks++)
#pragma unroll
            for (int mt = 0; mt < 4; mt++)
#pragma unroll
                for (int nt = 0; nt < 2; nt++)
                    acc[mt][nt] = __builtin_amdgcn_mfma_f32_16x16x32_bf16(
                        af[mt][ks], bfr[nt][ks], acc[mt][nt], 0, 0, 0);
        __builtin_amdgcn_s_setprio(0);
        read_b23(Bsd);
        SCHED_PIN();
        __builtin_amdgcn_s_barrier();

        // ---- phase 1: wait B23 -> Q2; then issue A47 reads ----
        if (t + 2 < NT) stage_half_A(Ab, Asd, row0, k2, 0, wid, lane);
        LGKM0();
        SCHED_PIN();
        __builtin_amdgcn_s_setprio(1);
#pragma unroll
        for (int ks = 0; ks < 2; ks++)
#pragma unroll
            for (int mt = 0; mt < 4; mt++)
#pragma unroll
                for (int nt = 0; nt < 2; nt++)
                    acc[mt][2 + nt] = __builtin_amdgcn_mfma_f32_16x16x32_bf16(
                        af[mt][ks], bfr[2 + nt][ks], acc[mt][2 + nt], 0, 0, 0);
        __builtin_amdgcn_s_setprio(0);
        read_a47(Asd);
        SCHED_PIN();
        __builtin_amdgcn_s_barrier();

        // ---- phase 2: wait A47 -> Q3 ----
        if (t + 2 < NT) stage_half_B(Bb, Bsd, col0, k2, 1, wid, lane);
        LGKM0();
        SCHED_PIN();
        __builtin_amdgcn_s_setprio(1);
#pragma unroll
        for (int ks = 0; ks < 2; ks++)
#pragma unroll
            for (int mt = 0; mt < 4; mt++)
#pragma unroll
                for (int nt = 0; nt < 2; nt++)
                    acc[4 + mt][2 + nt] = __builtin_amdgcn_mfma_f32_16x16x32_bf16(
                        af[mt][ks], bfr[2 + nt][ks], acc[4 + mt][2 + nt], 0, 0, 0);
        __builtin_amdgcn_s_setprio(0);
        SCHED_PIN();
        __builtin_amdgcn_s_barrier();

        // ---- phase 3: Q4 (no new reads needed); vmcnt; barrier; seam reads ----
        if (t + 2 < NT) stage_half_A(Ab, Asd, row0, k2, 1, wid, lane);
        __builtin_amdgcn_s_setprio(1);
#pragma unroll
        for (int ks = 0; ks < 2; ks++)
#pragma unroll
            for (int mt = 0; mt < 4; mt++)
#pragma unroll
                for (int nt = 0; nt < 2; nt++)
                    acc[4 + mt][nt] = __builtin_amdgcn_mfma_f32_16x16x32_bf16(
                        af[mt][ks], bfr[nt][ks], acc[4 + mt][nt], 0, 0, 0);
        __builtin_amdgcn_s_setprio(0);
        SCHED_PIN();
        if (t + 2 < NT) asm volatile("s_waitcnt vmcnt(6)" ::: "memory");
        else            asm volatile("s_waitcnt vmcnt(0)" ::: "memory");
        __builtin_amdgcn_s_barrier();
        if (t + 1 < NT) {   // seam: issue next tile's A03/B01 reads (stream under p0)
            read_a03(Asn); read_b01(Bsn);
            SCHED_PIN();
        }
    }

    // ---- epilogue: C/D layout col=lane&15, row=quad*4+reg [m89/m91-verified] ----
#pragma unroll
    for (int nt = 0; nt < 4; nt++) {
        const int col = col0 + wn * 64 + nt * 16 + l15;
        float bv = 0.f;
        if (MODE == MODE_PROJ_T || MODE == MODE_PROJ_N || MODE == MODE_OUT) bv = bias[col];
#pragma unroll
        for (int mt = 0; mt < 8; mt++) {
            const int rbase = row0 + wm * 128 + mt * 16 + quad * 4;
            if (MODE == MODE_PROJ_T) {
                // 4 consecutive rows per lane are contiguous ushorts: one 8B store
                ushort4 o;
                o.x = f2bf(acc[mt][nt][0] + bv); o.y = f2bf(acc[mt][nt][1] + bv);
                o.z = f2bf(acc[mt][nt][2] + bv); o.w = f2bf(acc[mt][nt][3] + bv);
                *(ushort4*)&((unsigned short*)Cout)[((size_t)(rbase >> 10) << 20) +
                                                    (size_t)col * 1024 + (rbase & 1023)] = o;
            } else {
#pragma unroll
                for (int r = 0; r < 4; r++) {
                    const int m = rbase + r;
                    float v = acc[mt][nt][r];
                    if (MODE == MODE_SCORES) v *= alpha;
                    v += bv;
                    if (MODE == MODE_SCORES) {
                        ((float*)Cout)[(size_t)bz * sC + (size_t)m * 1024 + col] = v;
                    } else if (MODE == MODE_OUT) {
                        ((float*)Cout)[(size_t)m * 1024 + col] = v;
                    } else { // MODE_PROJ_N || MODE_ATT
                        ((unsigned short*)Cout)[(size_t)bz * sC + (size_t)m * 1024 + col] = f2bf(v);
                    }
                }
            }
        }
    }
}

// batched / single-matrix launches, XCD-aware decode (hw round-robins id%8)
template<int MODE>
__global__ __launch_bounds__(512, 2) void gemm8(
    const __hip_bfloat16* __restrict__ A,
    const __hip_bfloat16* __restrict__ Bm,
    const float* __restrict__ bias,
    void* __restrict__ Cout,
    int K, long sA, long sB, long sC, float alpha)
{
    __shared__ __align__(16) short As[2 * 256 * 64];
    __shared__ __align__(16) short Bs[2 * 256 * 64];
    const int id = blockIdx.x;
    const int xcd = id & 7;
    const int s   = id >> 3;
    int by, bx, bz;
    if (MODE == MODE_SCORES || MODE == MODE_ATT) {
        bz = xcd + ((s >> 4) << 3);        // batches {j, j+8} on XCD j
        by = (s & 15) >> 2;
        bx = s & 3;
    } else {                                // M=16384: 64 row-blocks x 4 col-blocks
        bz = 0;
        by = ((s >> 2) << 3) | xcd;        // y%8 == xcd
        bx = s & 3;
    }
    gemm_body8<MODE>(A, Bm, bias, Cout, K, sA, sB, sC, alpha,
                     by * 256, bx * 256, bz, As, Bs);
}

// all three input projections in ONE 768-block dispatch
__global__ __launch_bounds__(512, 2) void gemm8_proj3(
    const __hip_bfloat16* __restrict__ qb, const __hip_bfloat16* __restrict__ kb,
    const __hip_bfloat16* __restrict__ vb,
    const __hip_bfloat16* __restrict__ wq, const __hip_bfloat16* __restrict__ wk,
    const __hip_bfloat16* __restrict__ wv,
    const float* __restrict__ biq, const float* __restrict__ bik,
    const float* __restrict__ biv,
    unsigned short* __restrict__ qT, unsigned short* __restrict__ kp,
    unsigned short* __restrict__ vT)
{
    __shared__ __align__(16) short As[2 * 256 * 64];
    __shared__ __align__(16) short Bs[2 * 256 * 64];
    const int id  = blockIdx.x;
    const int xcd = id & 7;
    const int s   = id >> 3;           // 0..95
    const int g   = s >> 5;            // 0:q 1:k 2:v
    const int s2  = s & 31;
    const int by  = ((s2 >> 2) << 3) | xcd;
    const int bx  = s2 & 3;
    const __hip_bfloat16* A;  const __hip_bfloat16* B;  const float* bias;  void* C;
    if      (g == 0) { A = qb; B = wq; bias = biq; C = qT; }
    else if (g == 1) { A = kb; B = wk; bias = bik; C = kp; }
    else             { A = vb; B = wv; bias = biv; C = vT; }
    if (g == 1) gemm_body8<MODE_PROJ_N>(A, B, bias, C, 1024, 0, 0, 0, 1.f,
                                        by * 256, bx * 256, 0, As, Bs);
    else        gemm_body8<MODE_PROJ_T>(A, B, bias, C, 1024, 0, 0, 0, 1.f,
                                        by * 256, bx * 256, 0, As, Bs);
}

// one wave per 1024-float row; 4 rows per 256-thread block
__global__ __launch_bounds__(256) void softmax_rows(
    const float* __restrict__ S, unsigned short* __restrict__ A)
{
    const int row  = blockIdx.x * 4 + (threadIdx.x >> 6);
    const int lane = threadIdx.x & 63;
    const float4* p = (const float4*)(S + (size_t)row * 1024);
    float4 v[4];
    float mx = -3.0e38f;
#pragma unroll
    for (int i = 0; i < 4; i++) {
        v[i] = p[lane + i * 64];
        mx = fmaxf(mx, fmaxf(fmaxf(v[i].x, v[i].y), fmaxf(v[i].z, v[i].w)));
    }
#pragma unroll
    for (int off = 32; off >= 1; off >>= 1) mx = fmaxf(mx, __shfl_xor(mx, off, 64));
    float e[16], sum = 0.f;
#pragma unroll
    for (int i = 0; i < 4; i++) {
        e[i*4+0] = __expf(v[i].x - mx); e[i*4+1] = __expf(v[i].y - mx);
        e[i*4+2] = __expf(v[i].z - mx); e[i*4+3] = __expf(v[i].w - mx);
        sum += e[i*4+0] + e[i*4+1] + e[i*4+2] + e[i*4+3];
    }
#pragma unroll
    for (int off = 32; off >= 1; off >>= 1) sum += __shfl_xor(sum, off, 64);
    const float inv = 1.0f / sum;
    ushort4* out = (ushort4*)(A + (size_t)row * 1024);
#pragma unroll
    for (int i = 0; i < 4; i++) {
        ushort4 o;
        o.x = f2bf(e[i*4+0] * inv); o.y = f2bf(e[i*4+1] * inv);
        o.z = f2bf(e[i*4+2] * inv); o.w = f2bf(e[i*4+3] * inv);
        out[lane + i * 64] = o;
    }
}

// all 7 f32->bf16 conversions in ONE dispatch
__global__ __launch_bounds__(256) void cvt_all(
    const float* __restrict__ q, const float* __restrict__ k, const float* __restrict__ v,
    const float* __restrict__ wq, const float* __restrict__ wk,
    const float* __restrict__ wv, const float* __restrict__ wo,
    unsigned short* __restrict__ qb, unsigned short* __restrict__ kb, unsigned short* __restrict__ vb,
    unsigned short* __restrict__ wqb, unsigned short* __restrict__ wkb,
    unsigned short* __restrict__ wvb, unsigned short* __restrict__ wob)
{
    const int id = blockIdx.x;
    const float* src; unsigned short* dst; int base;
    if      (id < 16384) { src = q;  dst = qb;  base = 0; }
    else if (id < 32768) { src = k;  dst = kb;  base = 16384; }
    else if (id < 49152) { src = v;  dst = vb;  base = 32768; }
    else if (id < 50176) { src = wq; dst = wqb; base = 49152; }
    else if (id < 51200) { src = wk; dst = wkb; base = 50176; }
    else if (id < 52224) { src = wv; dst = wvb; base = 51200; }
    else                 { src = wo; dst = wob; base = 52224; }
    const int i = (id - base) * 256 + threadIdx.x;
    const float4 vv = ((const float4*)src)[i];
    ushort4 o; o.x = f2bf(vv.x); o.y = f2bf(vv.y); o.z = f2bf(vv.z); o.w = f2bf(vv.w);
    ((ushort4*)dst)[i] = o;
}

extern "C" void kernel_launch(void* const* d_in, const int* in_sizes, int n_in,
                              void* d_out, int out_size, void* d_ws, size_t ws_size,
                              hipStream_t stream) {
    const float* query = (const float*)d_in[0];
    const float* key   = (const float*)d_in[1];
    const float* value = (const float*)d_in[2];
    const float* Wq = (const float*)d_in[3];  const float* bq = (const float*)d_in[4];
    const float* Wk = (const float*)d_in[5];  const float* bk = (const float*)d_in[6];
    const float* Wv = (const float*)d_in[7];  const float* bv = (const float*)d_in[8];
    const float* Wo = (const float*)d_in[9];  const float* bo = (const float*)d_in[10];

    char* ws = (char*)d_ws;
    const size_t MB = 1ull << 20;
    unsigned short* qbf = (unsigned short*)(ws + 0   * MB);   // 32MB
    unsigned short* kbf = (unsigned short*)(ws + 32  * MB);   // 32MB
    unsigned short* vbf = (unsigned short*)(ws + 64  * MB);   // 32MB
    unsigned short* wqb = (unsigned short*)(ws + 96  * MB);   // 2MB
    unsigned short* wkb = (unsigned short*)(ws + 98  * MB);
    unsigned short* wvb = (unsigned short*)(ws + 100 * MB);
    unsigned short* wob = (unsigned short*)(ws + 102 * MB);
    unsigned short* qT  = (unsigned short*)(ws + 104 * MB);   // [B,E,T] 32MB
    unsigned short* kp  = (unsigned short*)(ws + 136 * MB);   // [B,S,E] 32MB
    unsigned short* vT  = (unsigned short*)(ws + 168 * MB);   // [B,E,S] 32MB
    float*          sc  = (float*)(ws + 0 * MB);              // overlay qbf+kbf, 64MB
    unsigned short* att = (unsigned short*)(ws + 64 * MB);    // overlay vbf, 32MB
    unsigned short* ob  = (unsigned short*)(ws + 104 * MB);   // overlay qT, 32MB

    const long S1M = 1 << 20;
    dim3 blk(256);
    dim3 blk5(512);

    cvt_all<<<53248, blk, 0, stream>>>(query, key, value, Wq, Wk, Wv, Wo,
                                       qbf, kbf, vbf, wqb, wkb, wvb, wob);

    // projections: M=16384, N=1024, K=1024 — one 768-block dispatch (256^2 tiles)
    gemm8_proj3<<<768, blk5, 0, stream>>>(
        (const __hip_bfloat16*)qbf, (const __hip_bfloat16*)kbf, (const __hip_bfloat16*)vbf,
        (const __hip_bfloat16*)wqb, (const __hip_bfloat16*)wkb, (const __hip_bfloat16*)wvb,
        bq, bk, bv, qT, kp, vT);

    // scores: per-batch 1024x1024, batch pinned to XCD
    gemm8<MODE_SCORES><<<256, blk5, 0, stream>>>(
        (const __hip_bfloat16*)qT, (const __hip_bfloat16*)kp, nullptr, sc, 1024,
        S1M, S1M, S1M, 0.03125f);

    softmax_rows<<<4096, blk, 0, stream>>>(sc, att);

    gemm8<MODE_ATT><<<256, blk5, 0, stream>>>(
        (const __hip_bfloat16*)att, (const __hip_bfloat16*)vT, nullptr, ob, 1024,
        S1M, S1M, S1M, 1.f);

    gemm8<MODE_OUT><<<256, blk5, 0, stream>>>(
        (const __hip_bfloat16*)ob, (const __hip_bfloat16*)wob, bo, d_out, 1024, 0, 0, 0, 1.f);
}